// Round 1
// baseline (1100.109 us; speedup 1.0000x reference)
//
#include <hip/hip_runtime.h>

typedef unsigned short ushort_t;
typedef __attribute__((ext_vector_type(8))) short short8;
typedef __attribute__((ext_vector_type(4))) float f32x4;

#define DEV __device__ __forceinline__

DEV unsigned short f2bf(float f) {
  unsigned int u = __float_as_uint(f);
  u += 0x7FFFu + ((u >> 16) & 1u);           // round-to-nearest-even
  return (unsigned short)(u >> 16);
}
DEV float bf2f(unsigned short h) { return __uint_as_float(((unsigned int)h) << 16); }

DEV void gload_lds16(const void* g, void* l) {
  __builtin_amdgcn_global_load_lds((const __attribute__((address_space(1))) void*)g,
                                   (__attribute__((address_space(3))) void*)l, 16, 0, 0);
}

// ---------------------------------------------------------------- converts
__global__ void cvt_x_k(const float4* __restrict__ in, ushort4* __restrict__ out) {
  const int i = blockIdx.x * 256 + threadIdx.x;
  float4 f = in[i];
  out[i] = make_ushort4(f2bf(f.x), f2bf(f.y), f2bf(f.z), f2bf(f.w));
}

// in [R][Cn] f32 -> out [Cn][R] bf16   (tiled transpose)
__global__ __launch_bounds__(256)
void transp_k(const float* __restrict__ in, ushort_t* __restrict__ out, int R, int Cn) {
  __shared__ float tile[32][33];
  const int ctiles = Cn >> 5;
  const int bx = blockIdx.x % ctiles;
  const int by = blockIdx.x / ctiles;
  const int tx = threadIdx.x & 31, ty = threadIdx.x >> 5;
  #pragma unroll
  for (int i = 0; i < 4; ++i) {
    const int r = by * 32 + ty + i * 8;
    tile[ty + i * 8][tx] = in[(size_t)r * Cn + bx * 32 + tx];
  }
  __syncthreads();
  #pragma unroll
  for (int i = 0; i < 4; ++i) {
    const int cc = bx * 32 + ty + i * 8;
    out[(size_t)cc * R + by * 32 + tx] = f2bf(tile[tx][ty + i * 8]);
  }
}

// ---------------------------------------------------------------- big GEMMs
// C[m][n] = sum_k A[m][k]*BT[n][k]; 128x128 tile, BK=32, 4 waves, 16x16x32 MFMA.
// MODE 0: QKV epilogue (bias + relu/scale, scatter to q [B,H,N,d] and kT/vT [B,H,d,N])
// MODE 1: proj epilogue (bias, f32 out [M][768])
template <int MODE>
__global__ __launch_bounds__(256, 2)
void gemm_bt(const ushort_t* __restrict__ A, const ushort_t* __restrict__ BT,
             const float* __restrict__ bias,
             void* __restrict__ o0, void* __restrict__ o1, void* __restrict__ o2,
             int K, int ntiles) {
  constexpr int BK = 32;
  __shared__ __attribute__((aligned(16))) ushort_t As[128 * BK];
  __shared__ __attribute__((aligned(16))) ushort_t Bs[128 * BK];
  const int bid = blockIdx.x;
  const int nt = bid % ntiles, mt = bid / ntiles;
  const int t = threadIdx.x;
  const int w = t >> 6, l = t & 63;
  const int wr = w >> 1, wc = w & 1;
  const int lr = l & 15, lg = l >> 4;

  const ushort_t* Ap = A + (size_t)mt * 128 * K;
  const ushort_t* Bp = BT + (size_t)nt * 128 * K;

  f32x4 acc[4][4];
  #pragma unroll
  for (int i = 0; i < 4; ++i)
    #pragma unroll
    for (int j = 0; j < 4; ++j) acc[i][j] = (f32x4){0.f, 0.f, 0.f, 0.f};

  const int srow = t >> 2;        // 0..63
  const int scol = (t & 3) * 8;   // element offset within 32-elem row

  for (int k0 = 0; k0 < K; k0 += BK) {
    gload_lds16(Ap + (size_t)srow * K + k0 + scol,        &As[srow * BK + scol]);
    gload_lds16(Ap + (size_t)(srow + 64) * K + k0 + scol, &As[(srow + 64) * BK + scol]);
    gload_lds16(Bp + (size_t)srow * K + k0 + scol,        &Bs[srow * BK + scol]);
    gload_lds16(Bp + (size_t)(srow + 64) * K + k0 + scol, &Bs[(srow + 64) * BK + scol]);
    __syncthreads();
    short8 a[4], bfr[4];
    #pragma unroll
    for (int mf = 0; mf < 4; ++mf)
      a[mf] = *(const short8*)&As[(wr * 64 + mf * 16 + lr) * BK + lg * 8];
    #pragma unroll
    for (int nf = 0; nf < 4; ++nf)
      bfr[nf] = *(const short8*)&Bs[(wc * 64 + nf * 16 + lr) * BK + lg * 8];
    #pragma unroll
    for (int mf = 0; mf < 4; ++mf)
      #pragma unroll
      for (int nf = 0; nf < 4; ++nf)
        acc[mf][nf] = __builtin_amdgcn_mfma_f32_16x16x32_bf16(a[mf], bfr[nf], acc[mf][nf], 0, 0, 0);
    __syncthreads();
  }

  if (MODE == 0) {
    ushort_t* q  = (ushort_t*)o0;
    ushort_t* kT = (ushort_t*)o1;
    ushort_t* vT = (ushort_t*)o2;
    #pragma unroll
    for (int nf = 0; nf < 4; ++nf) {
      const int c3 = nt * 128 + wc * 64 + nf * 16 + lr;
      const float bv = bias[c3];
      const int s = c3 / 768;
      const int rem = c3 - s * 768;
      const int h = rem >> 6, dd = rem & 63;
      #pragma unroll
      for (int mf = 0; mf < 4; ++mf) {
        const int mbase = mt * 128 + wr * 64 + mf * 16 + lg * 4;
        #pragma unroll
        for (int r = 0; r < 4; ++r) {
          const int m = mbase + r;
          const int b_ = m / 3136;
          const int n = m - b_ * 3136;
          float v = acc[mf][nf][r] + bv;
          if (s == 0) {
            v = fmaxf(v, 0.f) * 0.125f;
            q[(((size_t)b_ * 12 + h) * 3136 + n) * 64 + dd] = f2bf(v);
          } else if (s == 1) {
            v = fmaxf(v, 0.f);
            kT[(((size_t)b_ * 12 + h) * 64 + dd) * 3136 + n] = f2bf(v);
          } else {
            vT[(((size_t)b_ * 12 + h) * 64 + dd) * 3136 + n] = f2bf(v);
          }
        }
      }
    }
  } else {
    float* O = (float*)o0;
    #pragma unroll
    for (int nf = 0; nf < 4; ++nf) {
      const int c = nt * 128 + wc * 64 + nf * 16 + lr;
      const float bv = bias[c];
      #pragma unroll
      for (int mf = 0; mf < 4; ++mf) {
        const int mbase = mt * 128 + wr * 64 + mf * 16 + lg * 4;
        #pragma unroll
        for (int r = 0; r < 4; ++r)
          O[(size_t)(mbase + r) * 768 + c] = acc[mf][nf][r] + bv;
      }
    }
  }
}

// ---------------------------------------------------------------- context = k^T v
// ctxT[bh][e][d] += sum_n kT[bh][d][n] * vT[bh][e][n]; 7 N-splits of 448, atomics.
__global__ __launch_bounds__(64)
void ctx_k(const ushort_t* __restrict__ kT, const ushort_t* __restrict__ vT,
           float* __restrict__ ctxT) {
  __shared__ __attribute__((aligned(16))) ushort_t Ks[64 * 64];
  __shared__ __attribute__((aligned(16))) ushort_t Vs[64 * 64];
  const int bid = blockIdx.x;
  const int s = bid % 7, bh = bid / 7;
  const int n0 = s * 448;
  const int t = threadIdx.x;
  const int lr = t & 15, lg = t >> 4;
  const ushort_t* kp = kT + (size_t)bh * 64 * 3136;
  const ushort_t* vp = vT + (size_t)bh * 64 * 3136;
  const int srow = t >> 3, scol = (t & 7) * 8;

  f32x4 acc[4][4];
  #pragma unroll
  for (int i = 0; i < 4; ++i)
    #pragma unroll
    for (int j = 0; j < 4; ++j) acc[i][j] = (f32x4){0.f, 0.f, 0.f, 0.f};

  for (int c = 0; c < 7; ++c) {
    const int nb = n0 + c * 64;
    #pragma unroll
    for (int i = 0; i < 8; ++i) {
      gload_lds16(kp + (size_t)(i * 8 + srow) * 3136 + nb + scol, &Ks[(i * 8 + srow) * 64 + scol]);
      gload_lds16(vp + (size_t)(i * 8 + srow) * 3136 + nb + scol, &Vs[(i * 8 + srow) * 64 + scol]);
    }
    __syncthreads();
    #pragma unroll
    for (int kk = 0; kk < 2; ++kk) {
      short8 a[4], bfr[4];
      #pragma unroll
      for (int mf = 0; mf < 4; ++mf)
        a[mf] = *(const short8*)&Ks[(mf * 16 + lr) * 64 + kk * 32 + lg * 8];
      #pragma unroll
      for (int nf = 0; nf < 4; ++nf)
        bfr[nf] = *(const short8*)&Vs[(nf * 16 + lr) * 64 + kk * 32 + lg * 8];
      #pragma unroll
      for (int mf = 0; mf < 4; ++mf)
        #pragma unroll
        for (int nf = 0; nf < 4; ++nf)
          acc[mf][nf] = __builtin_amdgcn_mfma_f32_16x16x32_bf16(a[mf], bfr[nf], acc[mf][nf], 0, 0, 0);
    }
    __syncthreads();
  }
  float* cp = ctxT + (size_t)bh * 4096;
  #pragma unroll
  for (int mf = 0; mf < 4; ++mf)
    #pragma unroll
    for (int nf = 0; nf < 4; ++nf)
      #pragma unroll
      for (int r = 0; r < 4; ++r)
        atomicAdd(&cp[(nf * 16 + lr) * 64 + mf * 16 + lg * 4 + r], acc[mf][nf][r]);
}

// ---------------------------------------------------------------- out = q @ ctx
// out[b][n][h*64+e] = sum_d q[bh][n][d] * ctx[d][e]   (ctxT stored [bh][e][d])
__global__ __launch_bounds__(256)
void attnout_k(const ushort_t* __restrict__ q, const float* __restrict__ ctxT,
               ushort_t* __restrict__ out) {
  __shared__ __attribute__((aligned(16))) ushort_t Qs[256 * 64];
  __shared__ __attribute__((aligned(16))) ushort_t Cs[64 * 64];
  const int bid = blockIdx.x;
  const int tile = bid % 13, bh = bid / 13;
  const int b_ = bh / 12, h = bh - b_ * 12;
  const int n0 = tile * 256;
  const int t = threadIdx.x;
  const int w = t >> 6, l = t & 63;
  const int lr = l & 15, lg = l >> 4;
  const ushort_t* qp = q + (size_t)bh * 3136 * 64;

  {  // stage ctx^T -> Cs (f32 -> bf16), linear
    const float4* cp = (const float4*)(ctxT + (size_t)bh * 4096);
    #pragma unroll
    for (int i = 0; i < 4; ++i) {
      const int j = i * 256 + t;
      float4 f = cp[j];
      ((ushort4*)Cs)[j] = make_ushort4(f2bf(f.x), f2bf(f.y), f2bf(f.z), f2bf(f.w));
    }
  }
  const int srow = t >> 3, scol = (t & 7) * 8;
  #pragma unroll
  for (int i = 0; i < 8; ++i)
    gload_lds16(qp + (size_t)(n0 + i * 32 + srow) * 64 + scol, &Qs[(i * 32 + srow) * 64 + scol]);
  __syncthreads();

  f32x4 acc[4][4];
  #pragma unroll
  for (int i = 0; i < 4; ++i)
    #pragma unroll
    for (int j = 0; j < 4; ++j) acc[i][j] = (f32x4){0.f, 0.f, 0.f, 0.f};

  #pragma unroll
  for (int kk = 0; kk < 2; ++kk) {
    short8 a[4], bfr[4];
    #pragma unroll
    for (int mf = 0; mf < 4; ++mf)
      a[mf] = *(const short8*)&Qs[(w * 64 + mf * 16 + lr) * 64 + kk * 32 + lg * 8];
    #pragma unroll
    for (int nf = 0; nf < 4; ++nf)
      bfr[nf] = *(const short8*)&Cs[(nf * 16 + lr) * 64 + kk * 32 + lg * 8];
    #pragma unroll
    for (int mf = 0; mf < 4; ++mf)
      #pragma unroll
      for (int nf = 0; nf < 4; ++nf)
        acc[mf][nf] = __builtin_amdgcn_mfma_f32_16x16x32_bf16(a[mf], bfr[nf], acc[mf][nf], 0, 0, 0);
  }

  ushort_t* op = out + (size_t)b_ * 3136 * 768 + h * 64;
  #pragma unroll
  for (int mf = 0; mf < 4; ++mf) {
    const int nb = n0 + w * 64 + mf * 16 + lg * 4;
    #pragma unroll
    for (int r = 0; r < 4; ++r) {
      const int n = nb + r;
      if (n < 3136) {
        #pragma unroll
        for (int nf = 0; nf < 4; ++nf)
          op[(size_t)n * 768 + nf * 16 + lr] = f2bf(acc[mf][nf][r]);
      }
    }
  }
}

// ---------------------------------------------------------------- depthwise 3x3
__global__ __launch_bounds__(768)
void dwconv_k(const ushort_t* __restrict__ in, const float* __restrict__ w9,
              const float* __restrict__ wb, ushort_t* __restrict__ out) {
  const int bn = blockIdx.x;
  const int b_ = bn / 3136, n = bn - b_ * 3136;
  const int y = n / 56, x = n - y * 56;
  const int c = threadIdx.x;
  const ushort_t* ip = in + (size_t)b_ * 3136 * 768 + c;
  float wv[9];
  #pragma unroll
  for (int i = 0; i < 9; ++i) wv[i] = w9[c * 9 + i];
  float acc = wb[c];
  #pragma unroll
  for (int dy = 0; dy < 3; ++dy) {
    const int yy = y + dy - 1;
    if ((unsigned)yy < 56u) {
      #pragma unroll
      for (int dx = 0; dx < 3; ++dx) {
        const int xx = x + dx - 1;
        if ((unsigned)xx < 56u)
          acc += bf2f(ip[(size_t)(yy * 56 + xx) * 768]) * wv[dy * 3 + dx];
      }
    }
  }
  out[(size_t)bn * 768 + c] = f2bf(acc);
}

// ---------------------------------------------------------------- launch
extern "C" void kernel_launch(void* const* d_in, const int* in_sizes, int n_in,
                              void* d_out, int out_size, void* d_ws, size_t ws_size,
                              hipStream_t stream) {
  (void)in_sizes; (void)n_in; (void)out_size; (void)ws_size;
  const float* x      = (const float*)d_in[0];
  const float* qkv_w  = (const float*)d_in[1];
  const float* qkv_b  = (const float*)d_in[2];
  const float* dw_w   = (const float*)d_in[3];
  const float* dw_b   = (const float*)d_in[4];
  const float* proj_w = (const float*)d_in[5];
  const float* proj_b = (const float*)d_in[6];
  float* out = (float*)d_out;

  char* ws = (char*)d_ws;
  const size_t SZ = (size_t)50176 * 768 * 2;  // 77,070,336 B per activation tensor
  ushort_t* xbf  = (ushort_t*)(ws);           // x bf16; later reused as attn-out
  ushort_t* attn = xbf;
  ushort_t* q    = (ushort_t*)(ws + SZ);      // q [B,H,N,d]; later reused as conv-out
  ushort_t* cvo  = q;
  ushort_t* kT   = (ushort_t*)(ws + 2 * SZ);  // [B,H,d,N]
  ushort_t* vT   = (ushort_t*)(ws + 3 * SZ);  // [B,H,d,N]
  ushort_t* wt1  = (ushort_t*)(ws + 4 * SZ);                        // qkv_w^T bf16 [2304][768]
  ushort_t* wt2  = (ushort_t*)(ws + 4 * SZ + 3538944);              // proj_w^T bf16 [768][768]
  float*    ctx  = (float*)(ws + 4 * SZ + 3538944 + 1179648);       // [192][64][64] f32

  hipMemsetAsync(ctx, 0, (size_t)192 * 4096 * 4, stream);
  cvt_x_k<<<37632, 256, 0, stream>>>((const float4*)x, (ushort4*)xbf);
  transp_k<<<1728, 256, 0, stream>>>(qkv_w, wt1, 768, 2304);
  transp_k<<<576, 256, 0, stream>>>(proj_w, wt2, 768, 768);
  gemm_bt<0><<<392 * 18, 256, 0, stream>>>(xbf, wt1, qkv_b, q, kT, vT, 768, 18);
  ctx_k<<<192 * 7, 64, 0, stream>>>(kT, vT, ctx);
  attnout_k<<<192 * 13, 256, 0, stream>>>(q, ctx, attn);
  dwconv_k<<<50176, 768, 0, stream>>>(attn, dw_w, dw_b, cvo);
  gemm_bt<1><<<392 * 6, 256, 0, stream>>>(cvo, wt2, proj_b, out, nullptr, nullptr, 768, 6);
}

// Round 3
// 1064.765 us; speedup vs baseline: 1.0332x; 1.0332x over previous
//
#include <hip/hip_runtime.h>

typedef unsigned short ushort_t;
typedef __attribute__((ext_vector_type(8))) short short8;
typedef __attribute__((ext_vector_type(4))) float f32x4;

#define DEV __device__ __forceinline__

DEV unsigned short f2bf(float f) {
  unsigned int u = __float_as_uint(f);
  u += 0x7FFFu + ((u >> 16) & 1u);           // round-to-nearest-even
  return (unsigned short)(u >> 16);
}
DEV float bf2f(unsigned short h) { return __uint_as_float(((unsigned int)h) << 16); }

DEV void gload_lds16(const void* g, void* l) {
  __builtin_amdgcn_global_load_lds((const __attribute__((address_space(1))) void*)g,
                                   (__attribute__((address_space(3))) void*)l, 16, 0, 0);
}

// ---------------------------------------------------------------- converts
__global__ void cvt_x_k(const float4* __restrict__ in, ushort4* __restrict__ out) {
  const int i = blockIdx.x * 256 + threadIdx.x;
  float4 f = in[i];
  out[i] = make_ushort4(f2bf(f.x), f2bf(f.y), f2bf(f.z), f2bf(f.w));
}

// in [R][Cn] f32 -> out [Cn][R] bf16   (tiled transpose)
__global__ __launch_bounds__(256)
void transp_k(const float* __restrict__ in, ushort_t* __restrict__ out, int R, int Cn) {
  __shared__ float tile[32][33];
  const int ctiles = Cn >> 5;
  const int bx = blockIdx.x % ctiles;
  const int by = blockIdx.x / ctiles;
  const int tx = threadIdx.x & 31, ty = threadIdx.x >> 5;
  #pragma unroll
  for (int i = 0; i < 4; ++i) {
    const int r = by * 32 + ty + i * 8;
    tile[ty + i * 8][tx] = in[(size_t)r * Cn + bx * 32 + tx];
  }
  __syncthreads();
  #pragma unroll
  for (int i = 0; i < 4; ++i) {
    const int cc = bx * 32 + ty + i * 8;
    out[(size_t)cc * R + by * 32 + tx] = f2bf(tile[tx][ty + i * 8]);
  }
}

// ---------------------------------------------------------------- big GEMMs
// C[m][n] = sum_k A[m][k]*BT[n][k]; 128x128 tile, BK=32, 4 waves, 16x16x32 MFMA.
// T1: bijective XCD-chunked blockIdx swizzle (grid % 8 == 0 for both calls) so
// the 18 (resp 6) n-tiles sharing one A panel run back-to-back on ONE XCD ->
// A panel stays in that XCD's private L2 instead of re-fetching from HBM.
// MODE 0: QKV epilogue (bias + relu/scale, scatter to q [B,H,N,d] and kT/vT [B,H,d,N])
// MODE 1: proj epilogue (bias, f32 out [M][768])
template <int MODE>
__global__ __launch_bounds__(256, 4)
void gemm_bt(const ushort_t* __restrict__ A, const ushort_t* __restrict__ BT,
             const float* __restrict__ bias,
             void* __restrict__ o0, void* __restrict__ o1, void* __restrict__ o2,
             int K, int ntiles) {
  constexpr int BK = 32;
  __shared__ __attribute__((aligned(16))) ushort_t As[128 * BK];
  __shared__ __attribute__((aligned(16))) ushort_t Bs[128 * BK];
  const int chunk = gridDim.x >> 3;                        // gridDim.x % 8 == 0
  const int bid = (blockIdx.x & 7) * chunk + (blockIdx.x >> 3);
  const int nt = bid % ntiles, mt = bid / ntiles;
  const int t = threadIdx.x;
  const int w = t >> 6, l = t & 63;
  const int wr = w >> 1, wc = w & 1;
  const int lr = l & 15, lg = l >> 4;

  const ushort_t* Ap = A + (size_t)mt * 128 * K;
  const ushort_t* Bp = BT + (size_t)nt * 128 * K;

  f32x4 acc[4][4];
  #pragma unroll
  for (int i = 0; i < 4; ++i)
    #pragma unroll
    for (int j = 0; j < 4; ++j) acc[i][j] = (f32x4){0.f, 0.f, 0.f, 0.f};

  const int srow = t >> 2;        // 0..63
  const int scol = (t & 3) * 8;   // element offset within 32-elem row

  for (int k0 = 0; k0 < K; k0 += BK) {
    gload_lds16(Ap + (size_t)srow * K + k0 + scol,        &As[srow * BK + scol]);
    gload_lds16(Ap + (size_t)(srow + 64) * K + k0 + scol, &As[(srow + 64) * BK + scol]);
    gload_lds16(Bp + (size_t)srow * K + k0 + scol,        &Bs[srow * BK + scol]);
    gload_lds16(Bp + (size_t)(srow + 64) * K + k0 + scol, &Bs[(srow + 64) * BK + scol]);
    __syncthreads();
    short8 a[4], bfr[4];
    #pragma unroll
    for (int mf = 0; mf < 4; ++mf)
      a[mf] = *(const short8*)&As[(wr * 64 + mf * 16 + lr) * BK + lg * 8];
    #pragma unroll
    for (int nf = 0; nf < 4; ++nf)
      bfr[nf] = *(const short8*)&Bs[(wc * 64 + nf * 16 + lr) * BK + lg * 8];
    #pragma unroll
    for (int mf = 0; mf < 4; ++mf)
      #pragma unroll
      for (int nf = 0; nf < 4; ++nf)
        acc[mf][nf] = __builtin_amdgcn_mfma_f32_16x16x32_bf16(a[mf], bfr[nf], acc[mf][nf], 0, 0, 0);
    __syncthreads();
  }

  if (MODE == 0) {
    ushort_t* q  = (ushort_t*)o0;
    ushort_t* kT = (ushort_t*)o1;
    ushort_t* vT = (ushort_t*)o2;
    #pragma unroll
    for (int nf = 0; nf < 4; ++nf) {
      const int c3 = nt * 128 + wc * 64 + nf * 16 + lr;
      const float bv = bias[c3];
      const int s = c3 / 768;
      const int rem = c3 - s * 768;
      const int h = rem >> 6, dd = rem & 63;
      #pragma unroll
      for (int mf = 0; mf < 4; ++mf) {
        const int mbase = mt * 128 + wr * 64 + mf * 16 + lg * 4;
        #pragma unroll
        for (int r = 0; r < 4; ++r) {
          const int m = mbase + r;
          const int b_ = m / 3136;
          const int n = m - b_ * 3136;
          float v = acc[mf][nf][r] + bv;
          if (s == 0) {
            v = fmaxf(v, 0.f) * 0.125f;
            q[(((size_t)b_ * 12 + h) * 3136 + n) * 64 + dd] = f2bf(v);
          } else if (s == 1) {
            v = fmaxf(v, 0.f);
            kT[(((size_t)b_ * 12 + h) * 64 + dd) * 3136 + n] = f2bf(v);
          } else {
            vT[(((size_t)b_ * 12 + h) * 64 + dd) * 3136 + n] = f2bf(v);
          }
        }
      }
    }
  } else {
    float* O = (float*)o0;
    #pragma unroll
    for (int nf = 0; nf < 4; ++nf) {
      const int c = nt * 128 + wc * 64 + nf * 16 + lr;
      const float bv = bias[c];
      #pragma unroll
      for (int mf = 0; mf < 4; ++mf) {
        const int mbase = mt * 128 + wr * 64 + mf * 16 + lg * 4;
        #pragma unroll
        for (int r = 0; r < 4; ++r)
          O[(size_t)(mbase + r) * 768 + c] = acc[mf][nf][r] + bv;
      }
    }
  }
}

// ---------------------------------------------------------------- context = k^T v
// ctxT[bh][e][d] += sum_n kT[bh][d][n] * vT[bh][e][n]; 7 N-splits of 448, atomics.
__global__ __launch_bounds__(64)
void ctx_k(const ushort_t* __restrict__ kT, const ushort_t* __restrict__ vT,
           float* __restrict__ ctxT) {
  __shared__ __attribute__((aligned(16))) ushort_t Ks[64 * 64];
  __shared__ __attribute__((aligned(16))) ushort_t Vs[64 * 64];
  const int bid = blockIdx.x;
  const int s = bid % 7, bh = bid / 7;
  const int n0 = s * 448;
  const int t = threadIdx.x;
  const int lr = t & 15, lg = t >> 4;
  const ushort_t* kp = kT + (size_t)bh * 64 * 3136;
  const ushort_t* vp = vT + (size_t)bh * 64 * 3136;
  const int srow = t >> 3, scol = (t & 7) * 8;

  f32x4 acc[4][4];
  #pragma unroll
  for (int i = 0; i < 4; ++i)
    #pragma unroll
    for (int j = 0; j < 4; ++j) acc[i][j] = (f32x4){0.f, 0.f, 0.f, 0.f};

  for (int c = 0; c < 7; ++c) {
    const int nb = n0 + c * 64;
    #pragma unroll
    for (int i = 0; i < 8; ++i) {
      gload_lds16(kp + (size_t)(i * 8 + srow) * 3136 + nb + scol, &Ks[(i * 8 + srow) * 64 + scol]);
      gload_lds16(vp + (size_t)(i * 8 + srow) * 3136 + nb + scol, &Vs[(i * 8 + srow) * 64 + scol]);
    }
    __syncthreads();
    #pragma unroll
    for (int kk = 0; kk < 2; ++kk) {
      short8 a[4], bfr[4];
      #pragma unroll
      for (int mf = 0; mf < 4; ++mf)
        a[mf] = *(const short8*)&Ks[(mf * 16 + lr) * 64 + kk * 32 + lg * 8];
      #pragma unroll
      for (int nf = 0; nf < 4; ++nf)
        bfr[nf] = *(const short8*)&Vs[(nf * 16 + lr) * 64 + kk * 32 + lg * 8];
      #pragma unroll
      for (int mf = 0; mf < 4; ++mf)
        #pragma unroll
        for (int nf = 0; nf < 4; ++nf)
          acc[mf][nf] = __builtin_amdgcn_mfma_f32_16x16x32_bf16(a[mf], bfr[nf], acc[mf][nf], 0, 0, 0);
    }
    __syncthreads();
  }
  float* cp = ctxT + (size_t)bh * 4096;
  #pragma unroll
  for (int mf = 0; mf < 4; ++mf)
    #pragma unroll
    for (int nf = 0; nf < 4; ++nf)
      #pragma unroll
      for (int r = 0; r < 4; ++r)
        atomicAdd(&cp[(nf * 16 + lr) * 64 + mf * 16 + lg * 4 + r], acc[mf][nf][r]);
}

// ---------------------------------------------------------------- out = q @ ctx
// out[b][n][h*64+e] = sum_d q[bh][n][d] * ctx[d][e]   (ctxT stored [bh][e][d])
__global__ __launch_bounds__(256)
void attnout_k(const ushort_t* __restrict__ q, const float* __restrict__ ctxT,
               ushort_t* __restrict__ out) {
  __shared__ __attribute__((aligned(16))) ushort_t Qs[256 * 64];
  __shared__ __attribute__((aligned(16))) ushort_t Cs[64 * 64];
  const int bid = blockIdx.x;
  const int tile = bid % 13, bh = bid / 13;
  const int b_ = bh / 12, h = bh - b_ * 12;
  const int n0 = tile * 256;
  const int t = threadIdx.x;
  const int w = t >> 6, l = t & 63;
  const int lr = l & 15, lg = l >> 4;
  const ushort_t* qp = q + (size_t)bh * 3136 * 64;

  {  // stage ctx^T -> Cs (f32 -> bf16), linear
    const float4* cp = (const float4*)(ctxT + (size_t)bh * 4096);
    #pragma unroll
    for (int i = 0; i < 4; ++i) {
      const int j = i * 256 + t;
      float4 f = cp[j];
      ((ushort4*)Cs)[j] = make_ushort4(f2bf(f.x), f2bf(f.y), f2bf(f.z), f2bf(f.w));
    }
  }
  const int srow = t >> 3, scol = (t & 7) * 8;
  #pragma unroll
  for (int i = 0; i < 8; ++i)
    gload_lds16(qp + (size_t)(n0 + i * 32 + srow) * 64 + scol, &Qs[(i * 32 + srow) * 64 + scol]);
  __syncthreads();

  f32x4 acc[4][4];
  #pragma unroll
  for (int i = 0; i < 4; ++i)
    #pragma unroll
    for (int j = 0; j < 4; ++j) acc[i][j] = (f32x4){0.f, 0.f, 0.f, 0.f};

  #pragma unroll
  for (int kk = 0; kk < 2; ++kk) {
    short8 a[4], bfr[4];
    #pragma unroll
    for (int mf = 0; mf < 4; ++mf)
      a[mf] = *(const short8*)&Qs[(w * 64 + mf * 16 + lr) * 64 + kk * 32 + lg * 8];
    #pragma unroll
    for (int nf = 0; nf < 4; ++nf)
      bfr[nf] = *(const short8*)&Cs[(nf * 16 + lr) * 64 + kk * 32 + lg * 8];
    #pragma unroll
    for (int mf = 0; mf < 4; ++mf)
      #pragma unroll
      for (int nf = 0; nf < 4; ++nf)
        acc[mf][nf] = __builtin_amdgcn_mfma_f32_16x16x32_bf16(a[mf], bfr[nf], acc[mf][nf], 0, 0, 0);
  }

  ushort_t* op = out + (size_t)b_ * 3136 * 768 + h * 64;
  #pragma unroll
  for (int mf = 0; mf < 4; ++mf) {
    const int nb = n0 + w * 64 + mf * 16 + lg * 4;
    #pragma unroll
    for (int r = 0; r < 4; ++r) {
      const int n = nb + r;
      if (n < 3136) {
        #pragma unroll
        for (int nf = 0; nf < 4; ++nf)
          op[(size_t)n * 768 + nf * 16 + lr] = f2bf(acc[mf][nf][r]);
      }
    }
  }
}

// ---------------------------------------------------------------- depthwise 3x3
__global__ __launch_bounds__(768)
void dwconv_k(const ushort_t* __restrict__ in, const float* __restrict__ w9,
              const float* __restrict__ wb, ushort_t* __restrict__ out) {
  const int bn = blockIdx.x;
  const int b_ = bn / 3136, n = bn - b_ * 3136;
  const int y = n / 56, x = n - y * 56;
  const int c = threadIdx.x;
  const ushort_t* ip = in + (size_t)b_ * 3136 * 768 + c;
  float wv[9];
  #pragma unroll
  for (int i = 0; i < 9; ++i) wv[i] = w9[c * 9 + i];
  float acc = wb[c];
  #pragma unroll
  for (int dy = 0; dy < 3; ++dy) {
    const int yy = y + dy - 1;
    if ((unsigned)yy < 56u) {
      #pragma unroll
      for (int dx = 0; dx < 3; ++dx) {
        const int xx = x + dx - 1;
        if ((unsigned)xx < 56u)
          acc += bf2f(ip[(size_t)(yy * 56 + xx) * 768]) * wv[dy * 3 + dx];
      }
    }
  }
  out[(size_t)bn * 768 + c] = f2bf(acc);
}

// ---------------------------------------------------------------- launch
extern "C" void kernel_launch(void* const* d_in, const int* in_sizes, int n_in,
                              void* d_out, int out_size, void* d_ws, size_t ws_size,
                              hipStream_t stream) {
  (void)in_sizes; (void)n_in; (void)out_size; (void)ws_size;
  const float* x      = (const float*)d_in[0];
  const float* qkv_w  = (const float*)d_in[1];
  const float* qkv_b  = (const float*)d_in[2];
  const float* dw_w   = (const float*)d_in[3];
  const float* dw_b   = (const float*)d_in[4];
  const float* proj_w = (const float*)d_in[5];
  const float* proj_b = (const float*)d_in[6];
  float* out = (float*)d_out;

  char* ws = (char*)d_ws;
  const size_t SZ = (size_t)50176 * 768 * 2;  // 77,070,336 B per activation tensor
  ushort_t* xbf  = (ushort_t*)(ws);           // x bf16; later reused as attn-out
  ushort_t* attn = xbf;
  ushort_t* q    = (ushort_t*)(ws + SZ);      // q [B,H,N,d]; later reused as conv-out
  ushort_t* cvo  = q;
  ushort_t* kT   = (ushort_t*)(ws + 2 * SZ);  // [B,H,d,N]
  ushort_t* vT   = (ushort_t*)(ws + 3 * SZ);  // [B,H,d,N]
  ushort_t* wt1  = (ushort_t*)(ws + 4 * SZ);                        // qkv_w^T bf16 [2304][768]
  ushort_t* wt2  = (ushort_t*)(ws + 4 * SZ + 3538944);              // proj_w^T bf16 [768][768]
  float*    ctx  = (float*)(ws + 4 * SZ + 3538944 + 1179648);       // [192][64][64] f32

  hipMemsetAsync(ctx, 0, (size_t)192 * 4096 * 4, stream);
  cvt_x_k<<<37632, 256, 0, stream>>>((const float4*)x, (ushort4*)xbf);
  transp_k<<<1728, 256, 0, stream>>>(qkv_w, wt1, 768, 2304);
  transp_k<<<576, 256, 0, stream>>>(proj_w, wt2, 768, 768);
  gemm_bt<0><<<392 * 18, 256, 0, stream>>>(xbf, wt1, qkv_b, q, kT, vT, 768, 18);
  ctx_k<<<192 * 7, 64, 0, stream>>>(kT, vT, ctx);
  attnout_k<<<192 * 13, 256, 0, stream>>>(q, ctx, attn);
  dwconv_k<<<50176, 768, 0, stream>>>(attn, dw_w, dw_b, cvo);
  gemm_bt<1><<<392 * 6, 256, 0, stream>>>(cvo, wt2, proj_b, out, nullptr, nullptr, 768, 6);
}